// Round 13
// baseline (282.920 us; speedup 1.0000x reference)
//
#include <hip/hip_runtime.h>
#include <math.h>

namespace {

constexpr int kB = 512, kI = 1152, kD = 8, kJ = 10, kC = 16;
constexpr int THREADS = 768;             // 12 waves; LDS 74.75 KB -> 2 blocks/CU
                                         // -> 24 waves/CU (75% occupancy cap)
constexpr int GRP = THREADS / 4;         // 192 i-groups; 4 threads (c4) per i
constexpr int ROWS = kI / GRP;           // 6 rows per thread
constexpr int NW = THREADS / 64;         // 12 waves
constexpr float EPS = 1e-7f;

// Round-13 = round-12 with THREADS 512->768 (single variable: wave count).
// Round-12 evidence: VALU issue = 30% busy matches instruction count exactly;
// the 70% idle is latency/barrier wait -> more resident waves is the lever.
// Round-8-vs-12 evidence: halving W L2-traffic (TB=2) LOST to TB=1 overlap,
// so W traffic is not binding; keep TB=1.
// VGPR must stay <= 85 for 6 waves/SIMD (round 11's 768-thread kernel: 84).
__launch_bounds__(THREADS)
__global__ void digitcaps_fused(const float* __restrict__ x,
                                const float* __restrict__ W,
                                float* __restrict__ out) {
  __shared__ float xhat[kI][kC];         // 73,728 B
  __shared__ float sredS[NW][kC];        // 768 B per-wave s partials
  __shared__ float sredZ[NW];            // 48 B
  __shared__ float vfac[kC];             // 64 B: v = fac * s (broadcast)

  const int t    = threadIdx.x;
  const int lane = t & 63;
  const int wid  = t >> 6;
  const int c4   = t & 3;
  const int g    = t >> 2;               // 0..191

  const int bid = blockIdx.x;
  const int j   = bid >> 9;              // j-major: 512 blocks share W[j] in L2
  const int b   = bid & 511;

  // ---------------- Phase 1: x_hat[i][c] = sum_d x[b,i,d] * W[j,i,d,c] ------
  #pragma unroll 3
  for (int it = 0; it < ROWS; ++it) {
    const int i = it * GRP + g;
    const float* Wp = W + (size_t)(j * kI + i) * (kD * kC) + (c4 << 2);
    const float4* xp = reinterpret_cast<const float4*>(x + (size_t)(b * kI + i) * kD);
    const float4 v0 = xp[0], v1 = xp[1];
    float xr[kD] = {v0.x, v0.y, v0.z, v0.w, v1.x, v1.y, v1.z, v1.w};
    float a0 = 0.f, a1 = 0.f, a2 = 0.f, a3 = 0.f;
    #pragma unroll
    for (int d = 0; d < kD; ++d) {
      const float4 w = *reinterpret_cast<const float4*>(Wp + d * kC);
      a0 += xr[d] * w.x; a1 += xr[d] * w.y;
      a2 += xr[d] * w.z; a3 += xr[d] * w.w;
    }
    float4 v4; v4.x = a0; v4.y = a1; v4.z = a2; v4.w = a3;
    *reinterpret_cast<float4*>(&xhat[i][c4 * 4]) = v4;
  }
  __syncthreads();

  // ---------------- Phase 2: 3 fused routing passes -------------------------
  float bl[ROWS];
  #pragma unroll
  for (int r = 0; r < ROWS; ++r) bl[r] = 0.f;

  #pragma unroll
  for (int pass = 0; pass < 3; ++pass) {
    float4 vv;
    if (pass > 0)                        // v from previous pass (one b128)
      vv = *reinterpret_cast<const float4*>(&vfac[c4 * 4]);

    float zp = 0.f, sp0 = 0.f, sp1 = 0.f, sp2 = 0.f, sp3 = 0.f;
    #pragma unroll
    for (int r = 0; r < ROWS; ++r) {
      const int i = r * GRP + g;
      const float4 h = *reinterpret_cast<const float4*>(&xhat[i][c4 * 4]);
      if (pass == 0) {
        // softmax(0) is uniform: c_i = 1/kI -> plain row sum, no exp.
        sp0 += h.x; sp1 += h.y; sp2 += h.z; sp3 += h.w;
      } else {
        // fused agreement + softmax-numerator accumulate
        float dp = vv.x * h.x + vv.y * h.y + vv.z * h.z + vv.w * h.w;
        dp += __shfl_xor(dp, 1, 64);     // sum across c4 (same row)
        dp += __shfl_xor(dp, 2, 64);
        bl[r] += dp;
        const float e = __expf(bl[r]);   // b bounded: |b| <= 2|v||xhat| < 6
        zp  += e;
        sp0 += e * h.x; sp1 += e * h.y; sp2 += e * h.z; sp3 += e * h.w;
      }
    }
    #pragma unroll
    for (int off = 4; off < 64; off <<= 1) {   // reduce over g within wave
      sp0 += __shfl_xor(sp0, off, 64);
      sp1 += __shfl_xor(sp1, off, 64);
      sp2 += __shfl_xor(sp2, off, 64);
      sp3 += __shfl_xor(sp3, off, 64);
      if (pass > 0) zp += __shfl_xor(zp, off, 64);
    }
    if (lane < 4) {                            // lane == c4 holds its partial
      float4 v4; v4.x = sp0; v4.y = sp1; v4.z = sp2; v4.w = sp3;
      *reinterpret_cast<float4*>(&sredS[wid][lane * 4]) = v4;
    }
    if (pass > 0 && lane == 0) sredZ[wid] = zp;
    __syncthreads();                           // partials ready

    // --- reducer: 16 threads combine, squash, publish v (or write out) ---
    if (t < kC) {
      float sr = 0.f;
      #pragma unroll
      for (int w = 0; w < NW; ++w) sr += sredS[w][t];
      float Z;
      if (pass == 0) {
        Z = (float)kI;
      } else {
        Z = 0.f;
        #pragma unroll
        for (int w = 0; w < NW; ++w) Z += sredZ[w];  // broadcast reads
      }
      const float sc = sr / Z;
      float pq = sc * sc;
      pq += __shfl_xor(pq, 1, 64);               // |s|^2 over 16 lanes
      pq += __shfl_xor(pq, 2, 64);
      pq += __shfl_xor(pq, 4, 64);
      pq += __shfl_xor(pq, 8, 64);
      const float nrm = sqrtf(pq);
      const float fac = pq / ((1.f + pq) * (nrm + EPS));
      const float vc = fac * sc;                 // v[t]
      if (pass < 2) vfac[t] = vc;
      else out[((size_t)b * kJ + j) * kC + t] = vc;
    }
    __syncthreads();                             // vfac ready / sredS reusable
    // Races: sredS/Z written pre-B1 of pass k, read by reducer between B1 and
    // B2, rewritten only after pass k+1's compute (post-B2). vfac written
    // between B1,B2 of pass k; read after B2 (start of pass k+1). Safe.
  }
}

}  // namespace

extern "C" void kernel_launch(void* const* d_in, const int* in_sizes, int n_in,
                              void* d_out, int out_size, void* d_ws, size_t ws_size,
                              hipStream_t stream) {
  (void)in_sizes; (void)n_in; (void)d_ws; (void)ws_size; (void)out_size;
  const float* x = reinterpret_cast<const float*>(d_in[0]);
  const float* W = reinterpret_cast<const float*>(d_in[1]);
  float* out = reinterpret_cast<float*>(d_out);
  const int grid = kB * kJ;  // 5120 blocks, j-major
  digitcaps_fused<<<grid, THREADS, 0, stream>>>(x, W, out);
}

// Round 14
// 184.655 us; speedup vs baseline: 1.5322x; 1.5322x over previous
//
#include <hip/hip_runtime.h>
#include <math.h>

namespace {

constexpr int kB = 512, kI = 1152, kD = 8, kJ = 10, kC = 16;
constexpr int THREADS = 512;             // 8 waves (768/GRP=192 regressed: r13)
constexpr int GRP = THREADS / 4;         // 128 i-groups; 4 threads (c4) per i
constexpr int ROWS = kI / GRP;           // 9 rows per thread
constexpr int NW = THREADS / 64;         // 8 waves
constexpr float EPS = 1e-7f;

// Round-14: round-12's fused 3-pass routing, but x_hat stays in REGISTERS.
// Round-12 insight: phase 2 reads exactly the elements this thread computed
// in phase 1 -> the x_hat LDS round-trip (9 writes + 27 reads of b128/thread)
// is pure overhead on the busiest pipe.
// Why it won't spill like rounds 3-7: (a) phase 2 is now the lean fused form
// (no per-thread max/broadcast state); (b) sched_barrier(0) after each
// phase-1 row pins the scheduler -> in-flight load demand capped at one row
// (~12 regs) instead of 9 rows hoisted; (c) full unroll keeps xh[] indices
// compile-time (partial unroll would force scratch).
// LDS drops 74.75 KB -> ~1.4 KB; occupancy becomes VGPR-bound.
__launch_bounds__(THREADS)
__global__ void digitcaps_fused(const float* __restrict__ x,
                                const float* __restrict__ W,
                                float* __restrict__ out) {
  __shared__ float sredS[NW][kC];        // 512 B per-wave s partials
  __shared__ float sredZ[NW];            // 32 B
  __shared__ float vfac[kC];             // 64 B: v = fac * s (broadcast)

  const int t    = threadIdx.x;
  const int lane = t & 63;
  const int wid  = t >> 6;
  const int c4   = t & 3;
  const int g    = t >> 2;               // 0..127

  const int bid = blockIdx.x;
  const int j   = bid >> 9;              // j-major: 512 blocks share W[j] in L2
  const int b   = bid & 511;

  float xh[ROWS][4];                     // register-resident x_hat fragments

  // ---------------- Phase 1: x_hat[i][c] = sum_d x[b,i,d] * W[j,i,d,c] ------
  #pragma unroll
  for (int it = 0; it < ROWS; ++it) {
    const int i = it * GRP + g;
    const float* Wp = W + (size_t)(j * kI + i) * (kD * kC) + (c4 << 2);
    const float4* xp = reinterpret_cast<const float4*>(x + (size_t)(b * kI + i) * kD);
    const float4 v0 = xp[0], v1 = xp[1];
    float xr[kD] = {v0.x, v0.y, v0.z, v0.w, v1.x, v1.y, v1.z, v1.w};
    float a0 = 0.f, a1 = 0.f, a2 = 0.f, a3 = 0.f;
    #pragma unroll
    for (int d = 0; d < kD; ++d) {
      const float4 w = *reinterpret_cast<const float4*>(Wp + d * kC);
      a0 += xr[d] * w.x; a1 += xr[d] * w.y;
      a2 += xr[d] * w.z; a3 += xr[d] * w.w;
    }
    xh[it][0] = a0; xh[it][1] = a1; xh[it][2] = a2; xh[it][3] = a3;
    // Pin scheduling: stop the next row's 10 loads being hoisted above this
    // row's FMAs (the register-demand explosion that spilled rounds 3-7).
    __builtin_amdgcn_sched_barrier(0);
  }
  // No barrier: xh is thread-private.

  // ---------------- Phase 2: 3 fused routing passes -------------------------
  float bl[ROWS];
  #pragma unroll
  for (int r = 0; r < ROWS; ++r) bl[r] = 0.f;

  #pragma unroll
  for (int pass = 0; pass < 3; ++pass) {
    float4 vv;
    if (pass > 0)                        // v from previous pass (one b128)
      vv = *reinterpret_cast<const float4*>(&vfac[c4 * 4]);

    float zp = 0.f, sp0 = 0.f, sp1 = 0.f, sp2 = 0.f, sp3 = 0.f;
    #pragma unroll
    for (int r = 0; r < ROWS; ++r) {
      if (pass == 0) {
        // softmax(0) is uniform: c_i = 1/kI -> plain row sum, no exp.
        sp0 += xh[r][0]; sp1 += xh[r][1]; sp2 += xh[r][2]; sp3 += xh[r][3];
      } else {
        // fused agreement + softmax-numerator accumulate
        float dp = vv.x * xh[r][0] + vv.y * xh[r][1]
                 + vv.z * xh[r][2] + vv.w * xh[r][3];
        dp += __shfl_xor(dp, 1, 64);     // sum across c4 (same row)
        dp += __shfl_xor(dp, 2, 64);
        bl[r] += dp;
        const float e = __expf(bl[r]);   // b bounded: |b| <= 2|v||xhat| < 6
        zp  += e;
        sp0 += e * xh[r][0]; sp1 += e * xh[r][1];
        sp2 += e * xh[r][2]; sp3 += e * xh[r][3];
      }
    }
    #pragma unroll
    for (int off = 4; off < 64; off <<= 1) {   // reduce over g within wave
      sp0 += __shfl_xor(sp0, off, 64);
      sp1 += __shfl_xor(sp1, off, 64);
      sp2 += __shfl_xor(sp2, off, 64);
      sp3 += __shfl_xor(sp3, off, 64);
      if (pass > 0) zp += __shfl_xor(zp, off, 64);
    }
    if (lane < 4) {                            // lane == c4 holds its partial
      float4 v4; v4.x = sp0; v4.y = sp1; v4.z = sp2; v4.w = sp3;
      *reinterpret_cast<float4*>(&sredS[wid][lane * 4]) = v4;
    }
    if (pass > 0 && lane == 0) sredZ[wid] = zp;
    __syncthreads();                           // B1: partials ready

    // --- reducer: 16 threads combine, squash, publish v (or write out) ---
    if (t < kC) {
      float sr = 0.f;
      #pragma unroll
      for (int w = 0; w < NW; ++w) sr += sredS[w][t];
      float Z;
      if (pass == 0) {
        Z = (float)kI;
      } else {
        Z = 0.f;
        #pragma unroll
        for (int w = 0; w < NW; ++w) Z += sredZ[w];
      }
      const float sc = sr / Z;
      float pq = sc * sc;
      pq += __shfl_xor(pq, 1, 64);               // |s|^2 over 16 lanes
      pq += __shfl_xor(pq, 2, 64);
      pq += __shfl_xor(pq, 4, 64);
      pq += __shfl_xor(pq, 8, 64);
      const float nrm = sqrtf(pq);
      const float fac = pq / ((1.f + pq) * (nrm + EPS));
      const float vc = fac * sc;                 // v[t]
      if (pass < 2) vfac[t] = vc;
      else out[((size_t)b * kJ + j) * kC + t] = vc;
    }
    __syncthreads();                             // B2: vfac ready, sred reusable
    // Races: sredS/Z written pre-B1 of pass k, read between B1/B2, rewritten
    // pre-B1 of pass k+1 (after B2). vfac written between B1/B2, read after
    // B2 by pass k+1. Safe with 2 barriers per pass.
  }
}

}  // namespace

extern "C" void kernel_launch(void* const* d_in, const int* in_sizes, int n_in,
                              void* d_out, int out_size, void* d_ws, size_t ws_size,
                              hipStream_t stream) {
  (void)in_sizes; (void)n_in; (void)d_ws; (void)ws_size; (void)out_size;
  const float* x = reinterpret_cast<const float*>(d_in[0]);
  const float* W = reinterpret_cast<const float*>(d_in[1]);
  float* out = reinterpret_cast<float*>(d_out);
  const int grid = kB * kJ;  // 5120 blocks, j-major
  digitcaps_fused<<<grid, THREADS, 0, stream>>>(x, W, out);
}